// Round 1
// baseline (474.112 us; speedup 1.0000x reference)
//
#include <hip/hip_runtime.h>
#include <hip/hip_bf16.h>

// Problem: B=8, N=4096, D=1024, H=8 heads (dh=128), NC=2. Image 64x64.
// Strategy: single-query attention => never materialize K/V GEMMs.
//   P1: s[b,n] = inputs[b,n]·W_enc + b_enc, argmax -> idx[b] (packed u64 atomicMax)
//   P2: Qp = Wq·Q+bq;  w[b,h,:] = Wk_h^T·Qp_h;  c[b,h] = Qp_h·bk_h
//   P3: fused feat=relu(in-Q) + depthwise3x3(+res+cb) -> logits[b,h,k]=w·x (split-partials)
//   P4: softmax over 4097 (incl cls token logit) -> A
//   P5: recompute x, y[b,h,:] = sum_k A[b,h,k]*x[b,k,:] (tile partials)
//   P6: y-reduce(+cls), O1 = Qp + Wv_h·y + bv, O2 = O1 + relu(Wo·O1+bo), out = Wfc·O2+bfc

#define NTOK 4096
#define DD 1024

// ---------------- ws float offsets ----------------
// argbest: 8 u64 at float offset 0..15
#define FO_CWT    64        // 9*1024
#define FO_QP     9472      // 8*1024
#define FO_W      17664     // 64*1024
#define FO_C      83200     // 64
#define FO_LPART  83264     // 4*64*4096
#define FO_A      1131840   // 64*4104 (stride 4104, k=0 is cls)
#define FO_YPART  1394496   // 16*64*1024
#define FO_Y      2443072   // 64*1024
#define FO_O1     2508608   // 8*1024
#define FO_O2     2516800   // 8*1024
#define A_STRIDE  4104
#define LPART_SPLIT_STRIDE 262144  // 8*8*4096

__global__ void k_init(const float* __restrict__ convw, float* __restrict__ cwT,
                       unsigned long long* __restrict__ argbest) {
  int gid = blockIdx.x * 256 + threadIdx.x;
  if (gid < 8) argbest[gid] = 0ull;
  for (int e = gid; e < 9216; e += gridDim.x * 256) {
    int d = e / 9, p = e - d * 9;
    cwT[p * DD + d] = convw[e];
  }
}

__global__ void k_argmax(const float* __restrict__ inp, const float* __restrict__ Wenc,
                         const float* __restrict__ benc, unsigned long long* __restrict__ argbest) {
  __shared__ unsigned long long best[4];
  int wave = threadIdx.x >> 6, lane = threadIdx.x & 63;
  int b = blockIdx.x >> 10;
  int row = ((blockIdx.x & 1023) << 2) + wave;
  const float4* rp = (const float4*)(inp + ((size_t)b * NTOK + row) * DD);
  const float4* wp = (const float4*)Wenc;
  float s = 0.f;
#pragma unroll
  for (int k = 0; k < 4; ++k) {
    float4 a = rp[lane + (k << 6)], x = wp[lane + (k << 6)];
    s = fmaf(a.x, x.x, s); s = fmaf(a.y, x.y, s);
    s = fmaf(a.z, x.z, s); s = fmaf(a.w, x.w, s);
  }
  for (int m = 32; m > 0; m >>= 1) s += __shfl_xor(s, m);
  if (lane == 0) {
    s += benc[0];
    unsigned u = __float_as_uint(s);
    u = (u & 0x80000000u) ? ~u : (u | 0x80000000u);
    best[wave] = ((unsigned long long)u << 32) | (unsigned long long)(0xFFFFFFFFu - (unsigned)row);
  }
  __syncthreads();
  if (threadIdx.x == 0) {
    unsigned long long m0 = best[0];
    for (int i = 1; i < 4; ++i) m0 = m0 > best[i] ? m0 : best[i];
    atomicMax(&argbest[b], m0);
  }
}

__global__ void k_qp(const float* __restrict__ inp, const float* __restrict__ Wq,
                     const float* __restrict__ bq, const unsigned long long* __restrict__ argbest,
                     float* __restrict__ Qp) {
  int wave = threadIdx.x >> 6, lane = threadIdx.x & 63;
  int b = blockIdx.x >> 8;
  int i = ((blockIdx.x & 255) << 2) + wave;
  unsigned idx = 0xFFFFFFFFu - (unsigned)(argbest[b] & 0xFFFFFFFFull);
  const float4* qr = (const float4*)(inp + ((size_t)b * NTOK + idx) * DD);
  const float4* wr = (const float4*)(Wq + (size_t)i * DD);
  float s = 0.f;
#pragma unroll
  for (int k = 0; k < 4; ++k) {
    float4 a = wr[lane + (k << 6)], x = qr[lane + (k << 6)];
    s = fmaf(a.x, x.x, s); s = fmaf(a.y, x.y, s);
    s = fmaf(a.z, x.z, s); s = fmaf(a.w, x.w, s);
  }
  for (int m = 32; m > 0; m >>= 1) s += __shfl_xor(s, m);
  if (lane == 0) Qp[b * DD + i] = s + bq[i];
}

__global__ void k_wc(const float* __restrict__ Wk, const float* __restrict__ bk,
                     const float* __restrict__ Qp, float* __restrict__ wbuf,
                     float* __restrict__ cbuf) {
  __shared__ float q[128];
  int tid = threadIdx.x;
  int b = blockIdx.x >> 3, h = blockIdx.x & 7;
  if (tid < 128) q[tid] = Qp[b * DD + h * 128 + tid];
  __syncthreads();
  if (tid == 0) {
    float cc = 0.f;
    for (int d = 0; d < 128; ++d) cc = fmaf(q[d], bk[h * 128 + d], cc);
    cbuf[b * 8 + h] = cc;
  }
  const float* Wkh = Wk + (size_t)(h * 128) * DD;
#pragma unroll
  for (int jj = 0; jj < 4; ++jj) {
    int j = tid + jj * 256;
    float s = 0.f;
    for (int d = 0; d < 128; ++d) s = fmaf(q[d], Wkh[d * DD + j], s);
    wbuf[(size_t)(b * 8 + h) * DD + j] = s;
  }
}

// ---- shared helpers for the two conv passes ----
__device__ __forceinline__ void stage_feat(float* lds, const float* inpb, const float* qrow,
                                           int R0, int C0, int jc, int tid) {
  int jgs = tid & 7, ts0 = tid >> 3;
  int js = jc + (jgs << 2);
  float4 qv = *(const float4*)(qrow + js);
  float4* lp = (float4*)lds;
  for (int t = ts0; t < 324; t += 32) {
    int tr = t / 18;
    int tc = t - tr * 18;
    int gr = R0 - 1 + tr, gc = C0 - 1 + tc;
    float4 v = make_float4(0.f, 0.f, 0.f, 0.f);
    if (gr >= 0 && gr < 64 && gc >= 0 && gc < 64) {
      float4 rv = *(const float4*)(inpb + (size_t)((gr << 6) + gc) * DD + js);
      v.x = fmaxf(rv.x - qv.x, 0.f);
      v.y = fmaxf(rv.y - qv.y, 0.f);
      v.z = fmaxf(rv.z - qv.z, 0.f);
      v.w = fmaxf(rv.w - qv.w, 0.f);
    }
    lp[jgs * 324 + t] = v;
  }
}

__device__ __forceinline__ float4 conv_x(const float4* fbase, int r, int c,
                                         const float4 cwr[9], float4 cb4) {
  float4 x4 = cb4;
  int t0 = r * 18 + c;
#pragma unroll
  for (int p = 0; p < 9; ++p) {
    int dr = p / 3, dc = p - dr * 3;
    float4 f = fbase[t0 + dr * 18 + dc];
    x4.x = fmaf(cwr[p].x, f.x, x4.x);
    x4.y = fmaf(cwr[p].y, f.y, x4.y);
    x4.z = fmaf(cwr[p].z, f.z, x4.z);
    x4.w = fmaf(cwr[p].w, f.w, x4.w);
    if (p == 4) { x4.x += f.x; x4.y += f.y; x4.z += f.z; x4.w += f.w; }  // residual
  }
  return x4;
}

// 512 blocks: b(8) x tile(16: 4x4 of 16x16 tokens) x split(4: 256ch)
__global__ __launch_bounds__(256, 2) void k_conv_logits(
    const float* __restrict__ inp, const float* __restrict__ convb,
    const float* __restrict__ cwT, const float* __restrict__ wbuf,
    const unsigned long long* __restrict__ argbest, float* __restrict__ Lpart) {
  __shared__ float lds[10368];
  const int tid = threadIdx.x, bx = blockIdx.x;
  const int b = bx >> 6, tile = (bx >> 2) & 15, split = bx & 3;
  const int R0 = (tile >> 2) << 4, C0 = (tile & 3) << 4;
  const int jbase = split << 8;
  const unsigned idxq = 0xFFFFFFFFu - (unsigned)(argbest[b] & 0xFFFFFFFFull);
  const int jg = tid >> 5, slot = tid & 31;
  const float* inpb = inp + (size_t)b * NTOK * DD;
  const float* qrow = inpb + (size_t)idxq * DD;

  float acc[8][8];
#pragma unroll
  for (int i = 0; i < 8; ++i)
#pragma unroll
    for (int h = 0; h < 8; ++h) acc[i][h] = 0.f;

  for (int cidx = 0; cidx < 8; ++cidx) {
    const int jc = jbase + (cidx << 5);
    __syncthreads();
    stage_feat(lds, inpb, qrow, R0, C0, jc, tid);
    const int j4 = jc + (jg << 2);
    float4 cwr[9];
#pragma unroll
    for (int p = 0; p < 9; ++p) cwr[p] = *(const float4*)(cwT + p * DD + j4);
    float4 cb4 = *(const float4*)(convb + j4);
    float4 wh[8];
#pragma unroll
    for (int h = 0; h < 8; ++h) wh[h] = *(const float4*)(wbuf + (size_t)(b * 8 + h) * DD + j4);
    __syncthreads();
    const float4* fbase = ((const float4*)lds) + jg * 324;
#pragma unroll
    for (int it = 0; it < 8; ++it) {
      const int tok = (it << 5) + slot;
      const int r = tok >> 4, c = tok & 15;
      float4 x4 = conv_x(fbase, r, c, cwr, cb4);
#pragma unroll
      for (int h = 0; h < 8; ++h) {
        float s = acc[it][h];
        s = fmaf(wh[h].x, x4.x, s); s = fmaf(wh[h].y, x4.y, s);
        s = fmaf(wh[h].z, x4.z, s); s = fmaf(wh[h].w, x4.w, s);
        acc[it][h] = s;
      }
    }
  }
  // reduce over jg (8 groups) via LDS, two rounds of 4 'it' each
  for (int round = 0; round < 2; ++round) {
    __syncthreads();
#pragma unroll
    for (int itl = 0; itl < 4; ++itl) {
#pragma unroll
      for (int h = 0; h < 8; ++h)
        lds[((jg * 4 + itl) * 32 + slot) * 8 + h] = acc[round * 4 + itl][h];
    }
    __syncthreads();
    for (int o = tid; o < 1024; o += 256) {
      float s = 0.f;
#pragma unroll
      for (int g = 0; g < 8; ++g) s += lds[g * 1024 + o];
      int tokl = round * 128 + (o >> 3);
      int h = o & 7;
      int gr = R0 + (tokl >> 4), gc = C0 + (tokl & 15);
      int gtok = (gr << 6) + gc;
      Lpart[(size_t)split * LPART_SPLIT_STRIDE + (size_t)(b * 8 + h) * NTOK + gtok] = s;
    }
  }
}

__global__ void k_softmax(const float* __restrict__ Lpart, const float* __restrict__ wbuf,
                          const float* __restrict__ cbuf, const float* __restrict__ cls,
                          float* __restrict__ Abuf) {
  __shared__ float red[256];
  int tid = threadIdx.x;
  int b = blockIdx.x >> 3, h = blockIdx.x & 7;
  float cval = cbuf[b * 8 + h];
  const float* wrow = wbuf + (size_t)(b * 8 + h) * DD;
  float p = 0.f;
  for (int j = tid; j < DD; j += 256) p = fmaf(wrow[j], cls[j], p);
  red[tid] = p; __syncthreads();
  for (int s = 128; s > 0; s >>= 1) { if (tid < s) red[tid] += red[tid + s]; __syncthreads(); }
  float l0 = (red[0] + cval) * 0.03125f;
  __syncthreads();
  float* Arow = Abuf + (size_t)(b * 8 + h) * A_STRIDE;
  const float* Lb = Lpart + (size_t)(b * 8 + h) * NTOK;
  float lmax = -1e30f;
  for (int k = tid; k < 4097; k += 256) {
    float l;
    if (k == 0) l = l0;
    else {
      int t = k - 1;
      l = (Lb[t] + Lb[LPART_SPLIT_STRIDE + t] + Lb[2 * LPART_SPLIT_STRIDE + t] +
           Lb[3 * LPART_SPLIT_STRIDE + t] + cval) * 0.03125f;
    }
    Arow[k] = l;
    lmax = fmaxf(lmax, l);
  }
  red[tid] = lmax; __syncthreads();
  for (int s = 128; s > 0; s >>= 1) { if (tid < s) red[tid] = fmaxf(red[tid], red[tid + s]); __syncthreads(); }
  float m = red[0];
  __syncthreads();
  float lsum = 0.f;
  for (int k = tid; k < 4097; k += 256) { float e = __expf(Arow[k] - m); Arow[k] = e; lsum += e; }
  red[tid] = lsum; __syncthreads();
  for (int s = 128; s > 0; s >>= 1) { if (tid < s) red[tid] += red[tid + s]; __syncthreads(); }
  float inv = 1.0f / red[0];
  for (int k = tid; k < 4097; k += 256) Arow[k] *= inv;
}

__global__ __launch_bounds__(256, 2) void k_conv_y(
    const float* __restrict__ inp, const float* __restrict__ convb,
    const float* __restrict__ cwT, const float* __restrict__ Abuf,
    const unsigned long long* __restrict__ argbest, float* __restrict__ ypart) {
  __shared__ float lds[10368];
  const int tid = threadIdx.x, bx = blockIdx.x;
  const int b = bx >> 6, tile = (bx >> 2) & 15, split = bx & 3;
  const int R0 = (tile >> 2) << 4, C0 = (tile & 3) << 4;
  const int jbase = split << 8;
  const unsigned idxq = 0xFFFFFFFFu - (unsigned)(argbest[b] & 0xFFFFFFFFull);
  const int jg = tid >> 5, slot = tid & 31;
  const float* inpb = inp + (size_t)b * NTOK * DD;
  const float* qrow = inpb + (size_t)idxq * DD;
  const float* Ab = Abuf + (size_t)b * 8 * A_STRIDE + 1;

  for (int cidx = 0; cidx < 8; ++cidx) {
    const int jc = jbase + (cidx << 5);
    __syncthreads();
    stage_feat(lds, inpb, qrow, R0, C0, jc, tid);
    const int j4 = jc + (jg << 2);
    float4 cwr[9];
#pragma unroll
    for (int p = 0; p < 9; ++p) cwr[p] = *(const float4*)(cwT + p * DD + j4);
    float4 cb4 = *(const float4*)(convb + j4);
    __syncthreads();
    const float4* fbase = ((const float4*)lds) + jg * 324;
    float4 y4[8];
#pragma unroll
    for (int h = 0; h < 8; ++h) y4[h] = make_float4(0.f, 0.f, 0.f, 0.f);
#pragma unroll
    for (int it = 0; it < 8; ++it) {
      const int tok = (it << 5) + slot;
      const int r = tok >> 4, c = tok & 15;
      const int gtok = ((R0 + r) << 6) + C0 + c;
      float4 x4 = conv_x(fbase, r, c, cwr, cb4);
#pragma unroll
      for (int h = 0; h < 8; ++h) {
        float a = Ab[h * A_STRIDE + gtok];
        y4[h].x = fmaf(a, x4.x, y4[h].x);
        y4[h].y = fmaf(a, x4.y, y4[h].y);
        y4[h].z = fmaf(a, x4.z, y4[h].z);
        y4[h].w = fmaf(a, x4.w, y4[h].w);
      }
    }
    // reduce over the 32 token-slots (lanes within each 32-half of the wave)
#pragma unroll
    for (int h = 0; h < 8; ++h) {
#pragma unroll
      for (int m = 16; m >= 1; m >>= 1) {
        y4[h].x += __shfl_xor(y4[h].x, m);
        y4[h].y += __shfl_xor(y4[h].y, m);
        y4[h].z += __shfl_xor(y4[h].z, m);
        y4[h].w += __shfl_xor(y4[h].w, m);
      }
    }
    if (slot == 0) {
#pragma unroll
      for (int h = 0; h < 8; ++h)
        *(float4*)(ypart + (size_t)(((tile << 3) + b) * 8 + h) * DD + j4) = y4[h];
    }
  }
}

__global__ void k_yred(const float* __restrict__ ypart, const float* __restrict__ Abuf,
                       const float* __restrict__ cls, float* __restrict__ ybuf) {
  int tid = threadIdx.x;
  int b = blockIdx.x >> 3, h = blockIdx.x & 7;
  int j4 = tid << 2;
  float4 s = make_float4(0.f, 0.f, 0.f, 0.f);
  for (int t = 0; t < 16; ++t) {
    float4 v = *(const float4*)(ypart + (size_t)(((t << 3) + b) * 8 + h) * DD + j4);
    s.x += v.x; s.y += v.y; s.z += v.z; s.w += v.w;
  }
  float a0 = Abuf[(size_t)(b * 8 + h) * A_STRIDE];
  float4 cv = *(const float4*)(cls + j4);
  s.x = fmaf(a0, cv.x, s.x); s.y = fmaf(a0, cv.y, s.y);
  s.z = fmaf(a0, cv.z, s.z); s.w = fmaf(a0, cv.w, s.w);
  *(float4*)(ybuf + (size_t)(b * 8 + h) * DD + j4) = s;
}

__global__ void k_o1(const float* __restrict__ Wv, const float* __restrict__ bv,
                     const float* __restrict__ Qp, const float* __restrict__ ybuf,
                     float* __restrict__ O1) {
  int wave = threadIdx.x >> 6, lane = threadIdx.x & 63;
  int b = blockIdx.x >> 8;
  int i = ((blockIdx.x & 255) << 2) + wave;
  int h = i >> 7;
  const float4* wr = (const float4*)(Wv + (size_t)i * DD);
  const float4* yr = (const float4*)(ybuf + (size_t)(b * 8 + h) * DD);
  float s = 0.f;
#pragma unroll
  for (int k = 0; k < 4; ++k) {
    float4 a = wr[lane + (k << 6)], x = yr[lane + (k << 6)];
    s = fmaf(a.x, x.x, s); s = fmaf(a.y, x.y, s);
    s = fmaf(a.z, x.z, s); s = fmaf(a.w, x.w, s);
  }
  for (int m = 32; m > 0; m >>= 1) s += __shfl_xor(s, m);
  if (lane == 0) O1[b * DD + i] = Qp[b * DD + i] + bv[i] + s;
}

__global__ void k_o2(const float* __restrict__ Wo, const float* __restrict__ bo,
                     const float* __restrict__ O1, float* __restrict__ O2) {
  int wave = threadIdx.x >> 6, lane = threadIdx.x & 63;
  int b = blockIdx.x >> 8;
  int i = ((blockIdx.x & 255) << 2) + wave;
  const float4* wr = (const float4*)(Wo + (size_t)i * DD);
  const float4* xr = (const float4*)(O1 + (size_t)b * DD);
  float s = 0.f;
#pragma unroll
  for (int k = 0; k < 4; ++k) {
    float4 a = wr[lane + (k << 6)], x = xr[lane + (k << 6)];
    s = fmaf(a.x, x.x, s); s = fmaf(a.y, x.y, s);
    s = fmaf(a.z, x.z, s); s = fmaf(a.w, x.w, s);
  }
  for (int m = 32; m > 0; m >>= 1) s += __shfl_xor(s, m);
  if (lane == 0) O2[b * DD + i] = O1[b * DD + i] + fmaxf(s + bo[i], 0.f);
}

__global__ void k_out(const float* __restrict__ Wfc, const float* __restrict__ bfc,
                      const float* __restrict__ O2, float* __restrict__ out) {
  int wave = threadIdx.x >> 6, lane = threadIdx.x & 63;
  for (int p = wave; p < 16; p += 4) {
    int b = p >> 1, cc = p & 1;
    const float4* o = (const float4*)(O2 + (size_t)b * DD);
    const float4* wr = (const float4*)(Wfc + (size_t)cc * DD);
    float s = 0.f;
#pragma unroll
    for (int k = 0; k < 4; ++k) {
      float4 a = o[lane + (k << 6)], x = wr[lane + (k << 6)];
      s = fmaf(a.x, x.x, s); s = fmaf(a.y, x.y, s);
      s = fmaf(a.z, x.z, s); s = fmaf(a.w, x.w, s);
    }
    for (int m = 32; m > 0; m >>= 1) s += __shfl_xor(s, m);
    if (lane == 0) out[p] = s + bfc[cc];
  }
}

extern "C" void kernel_launch(void* const* d_in, const int* in_sizes, int n_in,
                              void* d_out, int out_size, void* d_ws, size_t ws_size,
                              hipStream_t stream) {
  const float* inp   = (const float*)d_in[0];
  const float* Wenc  = (const float*)d_in[1];
  const float* benc  = (const float*)d_in[2];
  const float* cls   = (const float*)d_in[3];
  const float* convw = (const float*)d_in[4];
  const float* convb = (const float*)d_in[5];
  const float* Wq    = (const float*)d_in[6];
  const float* bq    = (const float*)d_in[7];
  const float* Wk    = (const float*)d_in[8];
  const float* bk    = (const float*)d_in[9];
  const float* Wv    = (const float*)d_in[10];
  const float* bv    = (const float*)d_in[11];
  const float* Wo    = (const float*)d_in[12];
  const float* bo    = (const float*)d_in[13];
  const float* Wfc   = (const float*)d_in[14];
  const float* bfc   = (const float*)d_in[15];
  float* out = (float*)d_out;
  float* W = (float*)d_ws;
  unsigned long long* argbest = (unsigned long long*)d_ws;
  float* cwT   = W + FO_CWT;
  float* Qp    = W + FO_QP;
  float* wbuf  = W + FO_W;
  float* cbuf  = W + FO_C;
  float* Lpart = W + FO_LPART;
  float* Abuf  = W + FO_A;
  float* ypart = W + FO_YPART;
  float* ybuf  = W + FO_Y;
  float* O1    = W + FO_O1;
  float* O2    = W + FO_O2;

  hipLaunchKernelGGL(k_init,        dim3(36),   dim3(256), 0, stream, convw, cwT, argbest);
  hipLaunchKernelGGL(k_argmax,      dim3(8192), dim3(256), 0, stream, inp, Wenc, benc, argbest);
  hipLaunchKernelGGL(k_qp,          dim3(2048), dim3(256), 0, stream, inp, Wq, bq, argbest, Qp);
  hipLaunchKernelGGL(k_wc,          dim3(64),   dim3(256), 0, stream, Wk, bk, Qp, wbuf, cbuf);
  hipLaunchKernelGGL(k_conv_logits, dim3(512),  dim3(256), 0, stream, inp, convb, cwT, wbuf, argbest, Lpart);
  hipLaunchKernelGGL(k_softmax,     dim3(64),   dim3(256), 0, stream, Lpart, wbuf, cbuf, cls, Abuf);
  hipLaunchKernelGGL(k_conv_y,      dim3(512),  dim3(256), 0, stream, inp, convb, cwT, Abuf, argbest, ypart);
  hipLaunchKernelGGL(k_yred,        dim3(64),   dim3(256), 0, stream, ypart, Abuf, cls, ybuf);
  hipLaunchKernelGGL(k_o1,          dim3(2048), dim3(256), 0, stream, Wv, bv, Qp, ybuf, O1);
  hipLaunchKernelGGL(k_o2,          dim3(2048), dim3(256), 0, stream, Wo, bo, O1, O2);
  hipLaunchKernelGGL(k_out,         dim3(1),    dim3(256), 0, stream, Wfc, bfc, O2, out);
}

// Round 2
// 418.249 us; speedup vs baseline: 1.1336x; 1.1336x over previous
//
#include <hip/hip_runtime.h>
#include <hip/hip_bf16.h>

// FRMIL: B=8, N=4096, D=1024, H=8 (dh=128), NC=2, image 64x64.
// Single-query attention: K/V GEMMs never materialized.
//  k_init:    cwT[p][d] transpose of conv weights
//  k_argmax1: per-block best (packed u64, no atomics)  k_argmax2: reduce -> idx[b]
//  k_qp:      Qp = Wq·Q+bq
//  k_wc:      w[b,h,:]=Wk_h^T·Qp_h, c=Qp_h·bk_h, l0=(w·cls+c)*scale
//  k_fused:   per (b, 8x8 tile): phase A logits+tile-softmax(m,S), phase B y_t
//  k_comb:    flash-combine 64 tiles + cls -> ybuf
//  k_o1/o2/out: tiny matvecs
//
// block=256: fused uses __launch_bounds__(256,2) targeting 2 blocks/CU (LDS 53KB)

#define NTOK 4096
#define DD 1024

// ---------------- ws float offsets ----------------
#define FO_ARG 0         // 8 u64 = 16 floats
#define FO_S1  16        // 2048 u64 = 4096 floats
#define FO_CWT 4160      // 9216
#define FO_QP  13376     // 8192
#define FO_W   21568     // 65536
#define FO_C   87104     // 64   (cval)
#define FO_C2  87168     // 64   (scaled cls logit)
#define FO_MS  87232     // 64bh * 64tile * 2 = 8192
#define FO_YP  95424     // 64bh * 64tile * 1024 = 4194304
#define FO_Y   4289728   // 65536
#define FO_O1  4355264   // 8192
#define FO_O2  4363456   // 8192   (end: 4371648 floats = 16.7 MB)

__global__ void k_init(const float* __restrict__ convw, float* __restrict__ cwT) {
  int gid = blockIdx.x * 256 + threadIdx.x;
  if (gid < 9216) {
    int d = gid / 9, p = gid - d * 9;
    cwT[p * DD + d] = convw[gid];
  }
}

// ---------- argmax: stage 1 (no atomics), stage 2 ----------
__global__ void k_argmax1(const float* __restrict__ inp, const float* __restrict__ Wenc,
                          const float* __restrict__ benc, unsigned long long* __restrict__ s1buf) {
  __shared__ unsigned long long lb[4];
  int wave = threadIdx.x >> 6, lane = threadIdx.x & 63;
  int b = blockIdx.x >> 8;
  int r0 = ((blockIdx.x & 255) << 4) + (wave << 2);
  const float4* base = (const float4*)(inp + ((size_t)b * NTOK + r0) * DD);
  const float4* wp = (const float4*)Wenc;
  float s0 = 0.f, s1 = 0.f, s2 = 0.f, s3 = 0.f;
#pragma unroll
  for (int k = 0; k < 4; ++k) {
    int off = lane + (k << 6);
    float4 w4 = wp[off];
    float4 a0 = base[off];
    float4 a1 = base[256 + off];
    float4 a2 = base[512 + off];
    float4 a3 = base[768 + off];
    s0 = fmaf(w4.x, a0.x, s0); s0 = fmaf(w4.y, a0.y, s0); s0 = fmaf(w4.z, a0.z, s0); s0 = fmaf(w4.w, a0.w, s0);
    s1 = fmaf(w4.x, a1.x, s1); s1 = fmaf(w4.y, a1.y, s1); s1 = fmaf(w4.z, a1.z, s1); s1 = fmaf(w4.w, a1.w, s1);
    s2 = fmaf(w4.x, a2.x, s2); s2 = fmaf(w4.y, a2.y, s2); s2 = fmaf(w4.z, a2.z, s2); s2 = fmaf(w4.w, a2.w, s2);
    s3 = fmaf(w4.x, a3.x, s3); s3 = fmaf(w4.y, a3.y, s3); s3 = fmaf(w4.z, a3.z, s3); s3 = fmaf(w4.w, a3.w, s3);
  }
#pragma unroll
  for (int mk = 32; mk >= 1; mk >>= 1) {
    s0 += __shfl_xor(s0, mk); s1 += __shfl_xor(s1, mk);
    s2 += __shfl_xor(s2, mk); s3 += __shfl_xor(s3, mk);
  }
  if (lane == 0) {
    float be = benc[0];
    float v[4] = {s0 + be, s1 + be, s2 + be, s3 + be};
    unsigned long long bst = 0ull;
#pragma unroll
    for (int i = 0; i < 4; ++i) {
      unsigned u = __float_as_uint(v[i]);
      u = (u & 0x80000000u) ? ~u : (u | 0x80000000u);
      unsigned long long p = ((unsigned long long)u << 32) |
                             (unsigned long long)(0xFFFFFFFFu - (unsigned)(r0 + i));
      bst = bst > p ? bst : p;
    }
    lb[wave] = bst;
  }
  __syncthreads();
  if (threadIdx.x == 0) {
    unsigned long long m = lb[0];
#pragma unroll
    for (int i = 1; i < 4; ++i) m = m > lb[i] ? m : lb[i];
    s1buf[blockIdx.x] = m;
  }
}

__global__ void k_argmax2(const unsigned long long* __restrict__ s1buf,
                          unsigned long long* __restrict__ argbest) {
  __shared__ unsigned long long red[256];
  int tid = threadIdx.x, b = blockIdx.x;
  red[tid] = s1buf[b * 256 + tid];
  __syncthreads();
  for (int s = 128; s > 0; s >>= 1) {
    if (tid < s) { unsigned long long o = red[tid + s]; if (o > red[tid]) red[tid] = o; }
    __syncthreads();
  }
  if (tid == 0) argbest[b] = red[0];
}

__global__ void k_qp(const float* __restrict__ inp, const float* __restrict__ Wq,
                     const float* __restrict__ bq, const unsigned long long* __restrict__ argbest,
                     float* __restrict__ Qp) {
  int wave = threadIdx.x >> 6, lane = threadIdx.x & 63;
  int b = blockIdx.x >> 8;
  int i = ((blockIdx.x & 255) << 2) + wave;
  unsigned idx = 0xFFFFFFFFu - (unsigned)(argbest[b] & 0xFFFFFFFFull);
  const float4* qr = (const float4*)(inp + ((size_t)b * NTOK + idx) * DD);
  const float4* wr = (const float4*)(Wq + (size_t)i * DD);
  float s = 0.f;
#pragma unroll
  for (int k = 0; k < 4; ++k) {
    float4 a = wr[lane + (k << 6)], x = qr[lane + (k << 6)];
    s = fmaf(a.x, x.x, s); s = fmaf(a.y, x.y, s);
    s = fmaf(a.z, x.z, s); s = fmaf(a.w, x.w, s);
  }
  for (int m = 32; m > 0; m >>= 1) s += __shfl_xor(s, m);
  if (lane == 0) Qp[b * DD + i] = s + bq[i];
}

__global__ void k_wc(const float* __restrict__ Wk, const float* __restrict__ bk,
                     const float* __restrict__ Qp, const float* __restrict__ cls,
                     float* __restrict__ wbuf, float* __restrict__ cbuf,
                     float* __restrict__ cbuf2) {
  __shared__ float q[128];
  __shared__ float red[256];
  int tid = threadIdx.x;
  int b = blockIdx.x >> 3, h = blockIdx.x & 7;
  if (tid < 128) q[tid] = Qp[b * DD + h * 128 + tid];
  __syncthreads();
  float cc = 0.f;
  if (tid == 0) {
    for (int d = 0; d < 128; ++d) cc = fmaf(q[d], bk[h * 128 + d], cc);
    cbuf[b * 8 + h] = cc;
  }
  const float* Wkh = Wk + (size_t)(h * 128) * DD;
  float p = 0.f;
#pragma unroll
  for (int jj = 0; jj < 4; ++jj) {
    int j = tid + (jj << 8);
    float s = 0.f;
    for (int d = 0; d < 128; ++d) s = fmaf(q[d], Wkh[d * DD + j], s);
    wbuf[(size_t)(b * 8 + h) * DD + j] = s;
    p = fmaf(s, cls[j], p);
  }
  red[tid] = p; __syncthreads();
  for (int s = 128; s > 0; s >>= 1) { if (tid < s) red[tid] += red[tid + s]; __syncthreads(); }
  if (tid == 0) cbuf2[b * 8 + h] = (red[0] + cc) * 0.03125f;
}

// ---------- fused conv + logits + tile-softmax + y ----------
// grid 512 = b(8) x tile(64: 8x8 grid of 8x8-token tiles); 256 threads.
// LDS: sred4 = staging [g(32 ch-float4)][100 halo pos] float4 (51.2 KB),
//      reused as logit-reduce region (16 KB). atile = e-values [h][64 tok].
__global__ __launch_bounds__(256, 2) void k_fused(
    const float* __restrict__ inp, const float* __restrict__ convb,
    const float* __restrict__ cwT, const float* __restrict__ wbuf,
    const float* __restrict__ cbuf, const unsigned long long* __restrict__ argbest,
    float2* __restrict__ msbuf, float* __restrict__ ypart) {
  __shared__ float4 sred4[3200];
  __shared__ float atile[512];
  const int tid = threadIdx.x, bx = blockIdx.x;
  const int b = bx >> 6, tile = bx & 63;
  const int R0 = (tile >> 3) << 3, C0 = (tile & 7) << 3;
  const unsigned idxq = 0xFFFFFFFFu - (unsigned)(argbest[b] & 0xFFFFFFFFull);
  const float* inpb = inp + (size_t)b * NTOK * DD;
  const float* qrow = inpb + (size_t)idxq * DD;
  // staging ids: 32 ch-groups x 8 pos-slots
  const int gg = tid & 31, ts = tid >> 5;
  // phase A compute ids: col ca(8) x rowquad rq(4) x ch-subgroup jg(8)
  const int ca = tid & 7, rq = (tid >> 3) & 3, jg = tid >> 5;
  const int r0a = rq << 1;

  float acc[2][8];
#pragma unroll
  for (int i = 0; i < 2; ++i)
#pragma unroll
    for (int h = 0; h < 8; ++h) acc[i][h] = 0.f;

  // ================= phase A: logits =================
  for (int cidx = 0; cidx < 8; ++cidx) {
    const int jc = cidx << 7;
    __syncthreads();
    {  // stage 128 channels of the 10x10 halo
      const int js = jc + (gg << 2);
      float4 qv = *(const float4*)(qrow + js);
      for (int t = ts; t < 100; t += 8) {
        int tr = t / 10, tc = t - tr * 10;
        int gr = R0 - 1 + tr, gc = C0 - 1 + tc;
        float4 v = make_float4(0.f, 0.f, 0.f, 0.f);
        if (gr >= 0 && gr < 64 && gc >= 0 && gc < 64) {
          float4 rv = *(const float4*)(inpb + (size_t)((gr << 6) + gc) * DD + js);
          v.x = fmaxf(rv.x - qv.x, 0.f); v.y = fmaxf(rv.y - qv.y, 0.f);
          v.z = fmaxf(rv.z - qv.z, 0.f); v.w = fmaxf(rv.w - qv.w, 0.f);
        }
        sred4[gg * 100 + t] = v;
      }
    }
    __syncthreads();
#pragma unroll
    for (int sub = 0; sub < 4; ++sub) {
      const int g = (sub << 3) + jg;
      const int j4 = jc + (g << 2);
      float4 cwr[9];
#pragma unroll
      for (int p = 0; p < 9; ++p) cwr[p] = *(const float4*)(cwT + p * DD + j4);
      float4 cb4 = *(const float4*)(convb + j4);
      const float4* fb = sred4 + g * 100;
      float4 x0 = cb4, x1 = cb4;
      {
        float4 rw[4][3];
#pragma unroll
        for (int rr = 0; rr < 4; ++rr)
#pragma unroll
          for (int dc = 0; dc < 3; ++dc)
            rw[rr][dc] = fb[(r0a + rr) * 10 + ca + dc];
#pragma unroll
        for (int dr = 0; dr < 3; ++dr)
#pragma unroll
          for (int dc = 0; dc < 3; ++dc) {
            float4 w = cwr[dr * 3 + dc];
            float4 f0 = rw[dr][dc], f1 = rw[dr + 1][dc];
            x0.x = fmaf(w.x, f0.x, x0.x); x0.y = fmaf(w.y, f0.y, x0.y);
            x0.z = fmaf(w.z, f0.z, x0.z); x0.w = fmaf(w.w, f0.w, x0.w);
            x1.x = fmaf(w.x, f1.x, x1.x); x1.y = fmaf(w.y, f1.y, x1.y);
            x1.z = fmaf(w.z, f1.z, x1.z); x1.w = fmaf(w.w, f1.w, x1.w);
          }
        x0.x += rw[1][1].x; x0.y += rw[1][1].y; x0.z += rw[1][1].z; x0.w += rw[1][1].w;
        x1.x += rw[2][1].x; x1.y += rw[2][1].y; x1.z += rw[2][1].z; x1.w += rw[2][1].w;
      }
#pragma unroll
      for (int h = 0; h < 8; ++h) {
        float4 whv = *(const float4*)(wbuf + (size_t)(b * 8 + h) * DD + j4);
        float a0 = acc[0][h], a1 = acc[1][h];
        a0 = fmaf(whv.x, x0.x, a0); a0 = fmaf(whv.y, x0.y, a0);
        a0 = fmaf(whv.z, x0.z, a0); a0 = fmaf(whv.w, x0.w, a0);
        a1 = fmaf(whv.x, x1.x, a1); a1 = fmaf(whv.y, x1.y, a1);
        a1 = fmaf(whv.z, x1.z, a1); a1 = fmaf(whv.w, x1.w, a1);
        acc[0][h] = a0; acc[1][h] = a1;
      }
    }
  }
  // ---- reduce logits over 8 ch-subgroups, tile-local softmax ----
  __syncthreads();
  float* red = (float*)sred4;
#pragma unroll
  for (int it = 0; it < 2; ++it)
#pragma unroll
    for (int h = 0; h < 8; ++h)
      red[jg * 512 + ((r0a + it) * 8 + ca) * 8 + h] = acc[it][h];
  __syncthreads();
  for (int o = tid; o < 512; o += 256) {
    float s = 0.f;
#pragma unroll
    for (int g = 0; g < 8; ++g) s += red[g * 512 + o];
    int h = o & 7, tok = o >> 3;
    atile[h * 64 + tok] = (s + cbuf[b * 8 + h]) * 0.03125f;
  }
  __syncthreads();
  {
    int hh = tid >> 5, sl = tid & 31;
    float l1 = atile[hh * 64 + sl], l2 = atile[hh * 64 + 32 + sl];
    float mx = fmaxf(l1, l2);
#pragma unroll
    for (int mk = 16; mk >= 1; mk >>= 1) mx = fmaxf(mx, __shfl_xor(mx, mk));
    float e1 = __expf(l1 - mx), e2 = __expf(l2 - mx);
    float Ssum = e1 + e2;
#pragma unroll
    for (int mk = 16; mk >= 1; mk >>= 1) Ssum += __shfl_xor(Ssum, mk);
    atile[hh * 64 + sl] = e1; atile[hh * 64 + 32 + sl] = e2;
    if (sl == 0) msbuf[(b * 8 + hh) * 64 + tile] = make_float2(mx, Ssum);
  }
  // ================= phase B: y_t =================
  const int gB = tid >> 3, cB = tid & 7;
  for (int cidx = 0; cidx < 8; ++cidx) {
    const int jc = cidx << 7;
    __syncthreads();
    {
      const int js = jc + (gg << 2);
      float4 qv = *(const float4*)(qrow + js);
      for (int t = ts; t < 100; t += 8) {
        int tr = t / 10, tc = t - tr * 10;
        int gr = R0 - 1 + tr, gc = C0 - 1 + tc;
        float4 v = make_float4(0.f, 0.f, 0.f, 0.f);
        if (gr >= 0 && gr < 64 && gc >= 0 && gc < 64) {
          float4 rv = *(const float4*)(inpb + (size_t)((gr << 6) + gc) * DD + js);
          v.x = fmaxf(rv.x - qv.x, 0.f); v.y = fmaxf(rv.y - qv.y, 0.f);
          v.z = fmaxf(rv.z - qv.z, 0.f); v.w = fmaxf(rv.w - qv.w, 0.f);
        }
        sred4[gg * 100 + t] = v;
      }
    }
    __syncthreads();
    const int j4 = jc + (gB << 2);
    float4 cwr[9];
#pragma unroll
    for (int p = 0; p < 9; ++p) cwr[p] = *(const float4*)(cwT + p * DD + j4);
    float4 cb4 = *(const float4*)(convb + j4);
    const float4* fb = sred4 + gB * 100;
    float4 y4[8];
#pragma unroll
    for (int h = 0; h < 8; ++h) y4[h] = make_float4(0.f, 0.f, 0.f, 0.f);
    float4 w0[3], w1[3], w2[3];
#pragma unroll
    for (int dc = 0; dc < 3; ++dc) { w0[dc] = fb[cB + dc]; w1[dc] = fb[10 + cB + dc]; }
#pragma unroll
    for (int r = 0; r < 8; ++r) {
#pragma unroll
      for (int dc = 0; dc < 3; ++dc) w2[dc] = fb[(r + 2) * 10 + cB + dc];
      float4 x4 = cb4;
#pragma unroll
      for (int dc = 0; dc < 3; ++dc) {
        float4 wa = cwr[dc], wb = cwr[3 + dc], wc = cwr[6 + dc];
        x4.x = fmaf(wa.x, w0[dc].x, x4.x); x4.y = fmaf(wa.y, w0[dc].y, x4.y);
        x4.z = fmaf(wa.z, w0[dc].z, x4.z); x4.w = fmaf(wa.w, w0[dc].w, x4.w);
        x4.x = fmaf(wb.x, w1[dc].x, x4.x); x4.y = fmaf(wb.y, w1[dc].y, x4.y);
        x4.z = fmaf(wb.z, w1[dc].z, x4.z); x4.w = fmaf(wb.w, w1[dc].w, x4.w);
        x4.x = fmaf(wc.x, w2[dc].x, x4.x); x4.y = fmaf(wc.y, w2[dc].y, x4.y);
        x4.z = fmaf(wc.z, w2[dc].z, x4.z); x4.w = fmaf(wc.w, w2[dc].w, x4.w);
      }
      x4.x += w1[1].x; x4.y += w1[1].y; x4.z += w1[1].z; x4.w += w1[1].w;
#pragma unroll
      for (int h = 0; h < 8; ++h) {
        float a = atile[h * 64 + (r << 3) + cB];
        y4[h].x = fmaf(a, x4.x, y4[h].x); y4[h].y = fmaf(a, x4.y, y4[h].y);
        y4[h].z = fmaf(a, x4.z, y4[h].z); y4[h].w = fmaf(a, x4.w, y4[h].w);
      }
#pragma unroll
      for (int dc = 0; dc < 3; ++dc) { w0[dc] = w1[dc]; w1[dc] = w2[dc]; }
    }
#pragma unroll
    for (int h = 0; h < 8; ++h)
#pragma unroll
      for (int mk = 4; mk >= 1; mk >>= 1) {
        y4[h].x += __shfl_xor(y4[h].x, mk);
        y4[h].y += __shfl_xor(y4[h].y, mk);
        y4[h].z += __shfl_xor(y4[h].z, mk);
        y4[h].w += __shfl_xor(y4[h].w, mk);
      }
    if (cB == 0) {
#pragma unroll
      for (int h = 0; h < 8; ++h)
        *(float4*)(ypart + ((size_t)(b * 8 + h) * 64 + tile) * DD + j4) = y4[h];
    }
  }
}

__global__ void k_comb(const float2* __restrict__ msbuf, const float* __restrict__ cbuf2,
                       const float* __restrict__ cls, const float* __restrict__ ypart,
                       float* __restrict__ ybuf) {
  __shared__ float wgt[64];
  __shared__ float wclss;
  int tid = threadIdx.x, bh = blockIdx.x;
  if (tid < 64) {
    float2 ms = msbuf[bh * 64 + tid];
    float m = ms.x, S = ms.y;
    float M = m;
#pragma unroll
    for (int mk = 32; mk >= 1; mk >>= 1) M = fmaxf(M, __shfl_xor(M, mk));
    float l0 = cbuf2[bh];
    M = fmaxf(M, l0);
    float w = __expf(m - M);
    float z = S * w;
#pragma unroll
    for (int mk = 32; mk >= 1; mk >>= 1) z += __shfl_xor(z, mk);
    float ec = __expf(l0 - M);
    float Z = z + ec;
    wgt[tid] = w / Z;
    if (tid == 0) wclss = ec / Z;
  }
  __syncthreads();
  int j4 = tid << 2;
  float4 cv = *(const float4*)(cls + j4);
  float wc = wclss;
  float4 acc = make_float4(wc * cv.x, wc * cv.y, wc * cv.z, wc * cv.w);
  const float* yp = ypart + (size_t)bh * 64 * DD + j4;
#pragma unroll 4
  for (int t = 0; t < 64; ++t) {
    float w = wgt[t];
    float4 v = *(const float4*)(yp + (size_t)t * DD);
    acc.x = fmaf(w, v.x, acc.x); acc.y = fmaf(w, v.y, acc.y);
    acc.z = fmaf(w, v.z, acc.z); acc.w = fmaf(w, v.w, acc.w);
  }
  *(float4*)(ybuf + (size_t)bh * DD + j4) = acc;
}

__global__ void k_o1(const float* __restrict__ Wv, const float* __restrict__ bv,
                     const float* __restrict__ Qp, const float* __restrict__ ybuf,
                     float* __restrict__ O1) {
  int wave = threadIdx.x >> 6, lane = threadIdx.x & 63;
  int b = blockIdx.x >> 8;
  int i = ((blockIdx.x & 255) << 2) + wave;
  int h = i >> 7;
  const float4* wr = (const float4*)(Wv + (size_t)i * DD);
  const float4* yr = (const float4*)(ybuf + (size_t)(b * 8 + h) * DD);
  float s = 0.f;
#pragma unroll
  for (int k = 0; k < 4; ++k) {
    float4 a = wr[lane + (k << 6)], x = yr[lane + (k << 6)];
    s = fmaf(a.x, x.x, s); s = fmaf(a.y, x.y, s);
    s = fmaf(a.z, x.z, s); s = fmaf(a.w, x.w, s);
  }
  for (int m = 32; m > 0; m >>= 1) s += __shfl_xor(s, m);
  if (lane == 0) O1[b * DD + i] = Qp[b * DD + i] + bv[i] + s;
}

__global__ void k_o2(const float* __restrict__ Wo, const float* __restrict__ bo,
                     const float* __restrict__ O1, float* __restrict__ O2) {
  int wave = threadIdx.x >> 6, lane = threadIdx.x & 63;
  int b = blockIdx.x >> 8;
  int i = ((blockIdx.x & 255) << 2) + wave;
  const float4* wr = (const float4*)(Wo + (size_t)i * DD);
  const float4* xr = (const float4*)(O1 + (size_t)b * DD);
  float s = 0.f;
#pragma unroll
  for (int k = 0; k < 4; ++k) {
    float4 a = wr[lane + (k << 6)], x = xr[lane + (k << 6)];
    s = fmaf(a.x, x.x, s); s = fmaf(a.y, x.y, s);
    s = fmaf(a.z, x.z, s); s = fmaf(a.w, x.w, s);
  }
  for (int m = 32; m > 0; m >>= 1) s += __shfl_xor(s, m);
  if (lane == 0) O2[b * DD + i] = O1[b * DD + i] + fmaxf(s + bo[i], 0.f);
}

__global__ void k_out(const float* __restrict__ Wfc, const float* __restrict__ bfc,
                      const float* __restrict__ O2, float* __restrict__ out) {
  int wave = threadIdx.x >> 6, lane = threadIdx.x & 63;
  for (int p = wave; p < 16; p += 4) {
    int b = p >> 1, cc = p & 1;
    const float4* o = (const float4*)(O2 + (size_t)b * DD);
    const float4* wr = (const float4*)(Wfc + (size_t)cc * DD);
    float s = 0.f;
#pragma unroll
    for (int k = 0; k < 4; ++k) {
      float4 a = o[lane + (k << 6)], x = wr[lane + (k << 6)];
      s = fmaf(a.x, x.x, s); s = fmaf(a.y, x.y, s);
      s = fmaf(a.z, x.z, s); s = fmaf(a.w, x.w, s);
    }
    for (int m = 32; m > 0; m >>= 1) s += __shfl_xor(s, m);
    if (lane == 0) out[p] = s + bfc[cc];
  }
}

extern "C" void kernel_launch(void* const* d_in, const int* in_sizes, int n_in,
                              void* d_out, int out_size, void* d_ws, size_t ws_size,
                              hipStream_t stream) {
  const float* inp   = (const float*)d_in[0];
  const float* Wenc  = (const float*)d_in[1];
  const float* benc  = (const float*)d_in[2];
  const float* cls   = (const float*)d_in[3];
  const float* convw = (const float*)d_in[4];
  const float* convb = (const float*)d_in[5];
  const float* Wq    = (const float*)d_in[6];
  const float* bq    = (const float*)d_in[7];
  const float* Wk    = (const float*)d_in[8];
  const float* bk    = (const float*)d_in[9];
  const float* Wv    = (const float*)d_in[10];
  const float* bv    = (const float*)d_in[11];
  const float* Wo    = (const float*)d_in[12];
  const float* bo    = (const float*)d_in[13];
  const float* Wfc   = (const float*)d_in[14];
  const float* bfc   = (const float*)d_in[15];
  float* out = (float*)d_out;
  float* W = (float*)d_ws;
  unsigned long long* argbest = (unsigned long long*)(W + FO_ARG);
  unsigned long long* s1buf   = (unsigned long long*)(W + FO_S1);
  float* cwT   = W + FO_CWT;
  float* Qp    = W + FO_QP;
  float* wbuf  = W + FO_W;
  float* cbuf  = W + FO_C;
  float* cbuf2 = W + FO_C2;
  float2* msbuf = (float2*)(W + FO_MS);
  float* ypart = W + FO_YP;
  float* ybuf  = W + FO_Y;
  float* O1    = W + FO_O1;
  float* O2    = W + FO_O2;

  hipLaunchKernelGGL(k_init,    dim3(36),   dim3(256), 0, stream, convw, cwT);
  hipLaunchKernelGGL(k_argmax1, dim3(2048), dim3(256), 0, stream, inp, Wenc, benc, s1buf);
  hipLaunchKernelGGL(k_argmax2, dim3(8),    dim3(256), 0, stream, s1buf, argbest);
  hipLaunchKernelGGL(k_qp,      dim3(2048), dim3(256), 0, stream, inp, Wq, bq, argbest, Qp);
  hipLaunchKernelGGL(k_wc,      dim3(64),   dim3(256), 0, stream, Wk, bk, Qp, cls, wbuf, cbuf, cbuf2);
  hipLaunchKernelGGL(k_fused,   dim3(512),  dim3(256), 0, stream, inp, convb, cwT, wbuf, cbuf, argbest, msbuf, ypart);
  hipLaunchKernelGGL(k_comb,    dim3(64),   dim3(256), 0, stream, msbuf, cbuf2, cls, ypart, ybuf);
  hipLaunchKernelGGL(k_o1,      dim3(2048), dim3(256), 0, stream, Wv, bv, Qp, ybuf, O1);
  hipLaunchKernelGGL(k_o2,      dim3(2048), dim3(256), 0, stream, Wo, bo, O1, O2);
  hipLaunchKernelGGL(k_out,     dim3(1),    dim3(256), 0, stream, Wfc, bfc, O2, out);
}